// Round 1
// baseline (120.537 us; speedup 1.0000x reference)
//
#include <hip/hip_runtime.h>

// Fused NCA step: perception(4 fixed 3x3 filters, wrap pad) -> 1x1 conv 32->16
// +bias+ReLU -> 1x1 conv 16->8 -> x + y*mask.
// B=16, C=8, H=W=512, HID=16. fp32 throughout (CDNA4 has no fp32 MFMA; this is
// a balanced VALU/HBM kernel: ~640 FMA/pixel vs ~68 B/pixel HBM).

constexpr int B = 16, C = 8, H = 512, W = 512, HID = 16;

__global__ __launch_bounds__(256) void nca_step_kernel(
    const float* __restrict__ x,
    const float* __restrict__ w1w,   // [16][32]
    const float* __restrict__ w1b,   // [16]
    const float* __restrict__ w2w,   // [8][16]
    const int*   __restrict__ mask,  // [B][1][H][W]
    float*       __restrict__ out)   // [B][C][H][W]
{
    // ---- block -> (batch, row-pair) with XCD-bijective swizzle ----
    // grid = B*H/2 = 4096 = 8 XCDs * 512: each XCD gets a contiguous chunk of
    // row-pairs so halo rows (y-1, y+2) hit the same XCD's L2.
    const int bid = blockIdx.x;
    const int l   = ((bid & 7) << 9) | (bid >> 3);   // bijective: 4096 % 8 == 0

    const int t  = threadIdx.x;
    const int rb = t >> 7;         // row within the pair (0/1)
    const int tx = t & 127;        // 128 threads * 4 px = 512 = W
    const int b  = l >> 8;         // batch
    const int pr = l & 255;        // row pair
    const int y  = (pr << 1) | rb;
    const int x0 = tx << 2;

    const int ym = (y - 1) & (H - 1);
    const int yp = (y + 1) & (H - 1);
    const int xl = (x0 - 1) & (W - 1);
    const int xr = (x0 + 4) & (W - 1);

    const float* xb = x + (size_t)b * C * H * W;

    // hid accumulators: 16 hidden ch x 4 pixels, init with bias
    float acc[HID][4];
#pragma unroll
    for (int h = 0; h < HID; ++h) {
        const float bv = w1b[h];   // uniform -> s_load
#pragma unroll
        for (int p = 0; p < 4; ++p) acc[h][p] = bv;
    }

#pragma unroll 1
    for (int c = 0; c < C; ++c) {
        const float* xc = xb + c * H * W;
        const float* rm = xc + ym * W;
        const float* rc = xc + (size_t)y * W;
        const float* rp = xc + yp * W;

        // 3 rows x 6 cols neighborhood for 4 pixels (vector center + wrap edges)
        const float4 am = *(const float4*)(rm + x0);
        const float4 ac = *(const float4*)(rc + x0);
        const float4 ap = *(const float4*)(rp + x0);
        const float cm[6] = {rm[xl], am.x, am.y, am.z, am.w, rm[xr]};
        const float cc[6] = {rc[xl], ac.x, ac.y, ac.z, ac.w, rc[xr]};
        const float cp[6] = {rp[xl], ap.x, ap.y, ap.z, ap.w, rp[xr]};

        // shared vertical pass: s = top + 2*mid + bot, d = bot - top
        float s[6], d[6];
#pragma unroll
        for (int i = 0; i < 6; ++i) {
            s[i] = fmaf(2.0f, cc[i], cm[i] + cp[i]);
            d[i] = cp[i] - cm[i];
        }

#pragma unroll
        for (int p = 0; p < 4; ++p) {
            const float ident = cc[p + 1];
            const float sx  = (s[p + 2] - s[p]) * 0.125f;
            const float sy  = fmaf(2.0f, d[p + 1], d[p] + d[p + 2]) * 0.125f;
            const float lap = fmaf(fmaf(2.0f, s[p + 1], s[p] + s[p + 2]),
                                   0.0625f, -ident);
            const float* wrow = w1w + c * 4;   // uniform base for this channel
#pragma unroll
            for (int h = 0; h < HID; ++h) {
                const float* wh = wrow + h * 32;   // uniform -> s_load, CSE'd over p
                acc[h][p] = fmaf(wh[0], ident, acc[h][p]);
                acc[h][p] = fmaf(wh[1], sx,    acc[h][p]);
                acc[h][p] = fmaf(wh[2], sy,    acc[h][p]);
                acc[h][p] = fmaf(wh[3], lap,   acc[h][p]);
            }
        }
    }

    // ReLU
#pragma unroll
    for (int h = 0; h < HID; ++h)
#pragma unroll
        for (int p = 0; p < 4; ++p) acc[h][p] = fmaxf(acc[h][p], 0.0f);

    const size_t pix = (size_t)y * W + x0;
    const int4 m4 = *(const int4*)(mask + (size_t)b * H * W + pix);
    const float mf0 = (float)m4.x, mf1 = (float)m4.y,
                mf2 = (float)m4.z, mf3 = (float)m4.w;

    float* ob = out + (size_t)b * C * H * W;
#pragma unroll
    for (int o = 0; o < C; ++o) {
        float v0 = 0.f, v1 = 0.f, v2 = 0.f, v3 = 0.f;
        const float* w2r = w2w + o * HID;
#pragma unroll
        for (int h = 0; h < HID; ++h) {
            const float wv = w2r[h];   // uniform -> s_load
            v0 = fmaf(wv, acc[h][0], v0);
            v1 = fmaf(wv, acc[h][1], v1);
            v2 = fmaf(wv, acc[h][2], v2);
            v3 = fmaf(wv, acc[h][3], v3);
        }
        const float4 xc4 = *(const float4*)(xb + o * H * W + pix);
        float4 r;
        r.x = fmaf(v0, mf0, xc4.x);
        r.y = fmaf(v1, mf1, xc4.y);
        r.z = fmaf(v2, mf2, xc4.z);
        r.w = fmaf(v3, mf3, xc4.w);
        *(float4*)(ob + o * H * W + pix) = r;
    }
}

extern "C" void kernel_launch(void* const* d_in, const int* in_sizes, int n_in,
                              void* d_out, int out_size, void* d_ws, size_t ws_size,
                              hipStream_t stream) {
    const float* x    = (const float*)d_in[0];
    const float* w1w  = (const float*)d_in[1];
    const float* w1b  = (const float*)d_in[2];
    const float* w2w  = (const float*)d_in[3];
    const int*   mask = (const int*)d_in[4];
    float* out = (float*)d_out;

    dim3 grid(B * H / 2);   // 4096 blocks (divisible by 8 -> bijective XCD swizzle)
    dim3 block(256);        // 2 rows per block, 4 px/thread
    hipLaunchKernelGGL(nca_step_kernel, grid, block, 0, stream,
                       x, w1w, w1b, w2w, mask, out);
}